// Round 4
// baseline (661.364 us; speedup 1.0000x reference)
//
#include <hip/hip_runtime.h>
#include <stdint.h>

#define BB  2
#define NN  100000
#define MM  16384
#define SS  3
#define EE  262144
#define CC  32     // COUT
#define HH  64     // HID
#define RR  16     // latent rows per block
#define TPB 256

typedef _Float16 half2_t __attribute__((ext_vector_type(2)));

// gelu (tanh approximation, matches jax.nn.gelu approximate=True)
__device__ __forceinline__ float gelu_tanh(float x){
  float u  = 0.7978845608028654f * fmaf(0.044715f * x, x * x, x);
  float e  = __expf(2.0f * u);
  float r  = __builtin_amdgcn_rcpf(e + 1.0f);
  return x * (1.0f - r);
}

// RTNE fp16 pair pack (unbiased rounding — RTZ would bias the dot products)
__device__ __forceinline__ uint32_t pack2(float a, float b){
  half2_t h; h.x = (_Float16)a; h.y = (_Float16)b;
  return __builtin_bit_cast(uint32_t, h);
}

__device__ __forceinline__ float dot2(uint32_t a, uint32_t b, float c){
#if __has_builtin(__builtin_amdgcn_fdot2)
  return __builtin_amdgcn_fdot2(__builtin_bit_cast(half2_t, a),
                                __builtin_bit_cast(half2_t, b), c, false);
#else
  half2_t ha = __builtin_bit_cast(half2_t, a), hb = __builtin_bit_cast(half2_t, b);
  return fmaf((float)ha.x, (float)hb.x, fmaf((float)ha.y, (float)hb.y, c));
#endif
}

// setup: pack W2 rows and W3 columns into fp16 pairs (RTNE)
extern "C" __global__ void magno_pack(const float* __restrict__ W2,
                                      const float* __restrict__ W3,
                                      uint32_t* __restrict__ W2h,
                                      uint32_t* __restrict__ W3Th){
  int i = blockIdx.x * blockDim.x + threadIdx.x;
  if (i < HH * HH / 2){                       // 2048: W2h[j][kp] = (W2[j][2kp], W2[j][2kp+1])
    int j = i >> 5, kp = i & 31;
    W2h[i] = pack2(W2[j * HH + 2 * kp], W2[j * HH + 2 * kp + 1]);
  }
  if (i < CC * HH / 2){                       // 1024: W3Th[jp][c] = (W3[c][2jp], W3[c][2jp+1])
    int jp = i >> 5, c = i & 31;
    W3Th[i] = pack2(W3[c * HH + 2 * jp], W3[c * HH + 2 * jp + 1]);
  }
}

extern "C" __global__ void __launch_bounds__(TPB)
__attribute__((amdgpu_waves_per_eu(4)))     // cap total regs at 128 -> no AGPR spill traffic
magno_main(const float* __restrict__ x_coord,
           const float* __restrict__ pndata,
           const float* __restrict__ lat,
           const int*   __restrict__ nbr_idx,
           const int*   __restrict__ row_idx,
           const float* __restrict__ W_lift,
           const float* __restrict__ b_lift,
           const float* __restrict__ W1,
           const float* __restrict__ b1,
           const uint32_t* __restrict__ W2h,   // [HH][HH/2] fp16 pairs
           const float* __restrict__ b2,
           const uint32_t* __restrict__ W3Th,  // [HH/2][CC] fp16 pairs (j-major)
           const float* __restrict__ b3,
           const float* __restrict__ Ws1,
           const float* __restrict__ bs1,
           const float* __restrict__ Ws2,
           const float* __restrict__ bs2,
           float* __restrict__ out)
{
  const int blocksPerBatch = MM / RR;            // 1024
  const int b   = blockIdx.x / blocksPerBatch;
  const int m0  = (blockIdx.x % blocksPerBatch) * RR;
  const int tid = threadIdx.x;

  __shared__ __align__(16) float vsh[RR * 68];   // lat part of layer1, padded stride 68
  __shared__ float acc [RR * CC];
  __shared__ float outc[RR * CC];
  __shared__ float swsh[RR * 4];                 // scale weights per row
  __shared__ float cinv[RR];                     // 1/max(count,1) per row

  // ---- per-block precompute: v[row] = lat@W1[:,2:4] + b1, and scale softmax weights ----
  for (int idx = tid; idx < RR * HH; idx += TPB){
    int r = idx >> 6, j = idx & 63;
    float l0 = lat[(m0 + r) * 2 + 0];
    float l1 = lat[(m0 + r) * 2 + 1];
    vsh[r * 68 + j] = fmaf(l0, W1[j * 4 + 2], fmaf(l1, W1[j * 4 + 3], b1[j]));
  }
  if (tid < RR){
    int m = m0 + tid;
    float l0 = lat[m * 2 + 0], l1 = lat[m * 2 + 1];
    float t[16];
    #pragma unroll
    for (int i = 0; i < 16; i++)
      t[i] = fmaxf(fmaf(l0, Ws1[i * 2 + 0], fmaf(l1, Ws1[i * 2 + 1], bs1[i])), 0.0f);
    float a0 = bs2[0], a1 = bs2[1], a2 = bs2[2];
    #pragma unroll
    for (int i = 0; i < 16; i++){
      a0 = fmaf(t[i], Ws2[0 * 16 + i], a0);
      a1 = fmaf(t[i], Ws2[1 * 16 + i], a1);
      a2 = fmaf(t[i], Ws2[2 * 16 + i], a2);
    }
    float mx = fmaxf(a0, fmaxf(a1, a2));
    float e0 = __expf(a0 - mx), e1 = __expf(a1 - mx), e2 = __expf(a2 - mx);
    float inv = 1.0f / (e0 + e1 + e2);
    swsh[tid * 4 + 0] = e0 * inv;
    swsh[tid * 4 + 1] = e1 * inv;
    swsh[tid * 4 + 2] = e2 * inv;
  }
  for (int idx = tid; idx < RR * CC; idx += TPB) outc[idx] = 0.0f;

  // ---- per-scale edge processing ----
  for (int s = 0; s < SS; s++){
    __syncthreads();
    for (int idx = tid; idx < RR * CC; idx += TPB) acc[idx] = 0.0f;
    __syncthreads();

    const int* rows = row_idx + (size_t)(b * SS + s) * EE;
    const int* nbrs = nbr_idx + (size_t)(b * SS + s) * EE;

    // binary search edge range [eb, ee) for rows in [m0, m0+RR)
    int lo = 0, hi = EE;
    while (lo < hi){ int mid = (lo + hi) >> 1; if (rows[mid] < m0) lo = mid + 1; else hi = mid; }
    const int eb = lo;
    lo = eb; hi = EE;
    while (lo < hi){ int mid = (lo + hi) >> 1; if (rows[mid] < m0 + RR) lo = mid + 1; else hi = mid; }
    const int ee = lo;

    // per-row counts via binary search (rows sorted)
    if (tid < RR){
      int target = m0 + tid;
      int l0 = eb, h0 = ee;
      while (l0 < h0){ int mid = (l0 + h0) >> 1; if (rows[mid] < target) l0 = mid + 1; else h0 = mid; }
      int l1 = l0, h1b = ee;
      while (l1 < h1b){ int mid = (l1 + h1b) >> 1; if (rows[mid] < target + 1) l1 = mid + 1; else h1b = mid; }
      float c = (float)(l1 - l0);
      cinv[tid] = 1.0f / fmaxf(c, 1.0f);
    }
    __syncthreads();

    for (int e = eb + tid; e < ee; e += TPB){
      const int row = rows[e] - m0;
      const int nbr = nbrs[e];
      const float2 xc = *(const float2*)&x_coord[((size_t)b * NN + nbr) * 2];

      // layer 1 (fp32) -> packed fp16 h1 pairs
      uint32_t h1p[HH / 2];
      const float4* vr = (const float4*)&vsh[row * 68];
      #pragma unroll
      for (int q = 0; q < 16; q++){
        float4 vv = vr[q];
        float g0 = gelu_tanh(fmaf(xc.x, W1[(4*q+0)*4+0], fmaf(xc.y, W1[(4*q+0)*4+1], vv.x)));
        float g1 = gelu_tanh(fmaf(xc.x, W1[(4*q+1)*4+0], fmaf(xc.y, W1[(4*q+1)*4+1], vv.y)));
        float g2 = gelu_tanh(fmaf(xc.x, W1[(4*q+2)*4+0], fmaf(xc.y, W1[(4*q+2)*4+1], vv.z)));
        float g3 = gelu_tanh(fmaf(xc.x, W1[(4*q+3)*4+0], fmaf(xc.y, W1[(4*q+3)*4+1], vv.w)));
        h1p[2*q+0] = pack2(g0, g1);
        h1p[2*q+1] = pack2(g2, g3);
      }

      // layers 2+3 fused, fp16 dot2 with fp32 accumulate
      float a3[CC];
      #pragma unroll
      for (int c = 0; c < CC; c++) a3[c] = 0.0f;

      #pragma unroll 2
      for (int jp = 0; jp < HH / 2; jp++){
        const uint32_t* w2a = &W2h[(2*jp+0) * (HH/2)];
        const uint32_t* w2b = &W2h[(2*jp+1) * (HH/2)];
        float ta0=0.f, ta1=0.f, ta2=0.f, ta3=0.f;
        float tb0=0.f, tb1=0.f, tb2=0.f, tb3=0.f;
        #pragma unroll
        for (int i = 0; i < HH/2; i += 4){
          ta0 = dot2(h1p[i+0], w2a[i+0], ta0);
          ta1 = dot2(h1p[i+1], w2a[i+1], ta1);
          ta2 = dot2(h1p[i+2], w2a[i+2], ta2);
          ta3 = dot2(h1p[i+3], w2a[i+3], ta3);
          tb0 = dot2(h1p[i+0], w2b[i+0], tb0);
          tb1 = dot2(h1p[i+1], w2b[i+1], tb1);
          tb2 = dot2(h1p[i+2], w2b[i+2], tb2);
          tb3 = dot2(h1p[i+3], w2b[i+3], tb3);
        }
        float h2a = gelu_tanh(b2[2*jp+0] + ((ta0+ta1)+(ta2+ta3)));
        float h2b = gelu_tanh(b2[2*jp+1] + ((tb0+tb1)+(tb2+tb3)));
        uint32_t hp = pack2(h2a, h2b);
        const uint32_t* w3r = &W3Th[jp * CC];
        #pragma unroll
        for (int c = 0; c < CC; c++) a3[c] = dot2(hp, w3r[c], a3[c]);
      }

      // lift (on the fly) + LDS accumulate
      const float p0 = pndata[((size_t)b * NN + nbr) * 3 + 0];
      const float p1 = pndata[((size_t)b * NN + nbr) * 3 + 1];
      const float p2 = pndata[((size_t)b * NN + nbr) * 3 + 2];
      #pragma unroll
      for (int c = 0; c < CC; c++){
        float kv = a3[c] + b3[c];
        float pv = fmaf(p0, W_lift[c*3+0], fmaf(p1, W_lift[c*3+1], fmaf(p2, W_lift[c*3+2], b_lift[c])));
        atomicAdd(&acc[row * CC + c], kv * pv);
      }
    }

    __syncthreads();
    for (int idx = tid; idx < RR * CC; idx += TPB){
      int r = idx >> 5;
      outc[idx] = fmaf(swsh[r * 4 + s], acc[idx] * cinv[r], outc[idx]);
    }
  }

  __syncthreads();
  float* ob = out + ((size_t)b * MM + m0) * CC;
  for (int idx = tid; idx < RR * CC; idx += TPB) ob[idx] = outc[idx];
}

extern "C" void kernel_launch(void* const* d_in, const int* in_sizes, int n_in,
                              void* d_out, int out_size, void* d_ws, size_t ws_size,
                              hipStream_t stream)
{
  const float* x_coord = (const float*)d_in[0];
  const float* pndata  = (const float*)d_in[1];
  const float* lat     = (const float*)d_in[2];
  const int*   nbr_idx = (const int*)d_in[3];
  const int*   row_idx = (const int*)d_in[4];
  const float* W_lift  = (const float*)d_in[5];
  const float* b_lift  = (const float*)d_in[6];
  const float* W1      = (const float*)d_in[7];
  const float* b1      = (const float*)d_in[8];
  const float* W2      = (const float*)d_in[9];
  const float* b2      = (const float*)d_in[10];
  const float* W3      = (const float*)d_in[11];
  const float* b3      = (const float*)d_in[12];
  const float* Ws1     = (const float*)d_in[13];
  const float* bs1     = (const float*)d_in[14];
  const float* Ws2     = (const float*)d_in[15];
  const float* bs2     = (const float*)d_in[16];
  float* out = (float*)d_out;

  uint32_t* W2h  = (uint32_t*)d_ws;              // 2048 dwords
  uint32_t* W3Th = W2h + HH * HH / 2;            // 1024 dwords  (12 KB total)

  hipLaunchKernelGGL(magno_pack, dim3(8), dim3(256), 0, stream, W2, W3, W2h, W3Th);

  dim3 grid(BB * (MM / RR));
  dim3 block(TPB);
  hipLaunchKernelGGL(magno_main, grid, block, 0, stream,
                     x_coord, pndata, lat, nbr_idx, row_idx,
                     W_lift, b_lift, W1, b1, W2h, b2, W3Th, b3,
                     Ws1, bs1, Ws2, bs2, out);
}

// Round 5
// 345.854 us; speedup vs baseline: 1.9123x; 1.9123x over previous
//
#include <hip/hip_runtime.h>
#include <stdint.h>

#define BB  2
#define NN  100000
#define MM  16384
#define SS  3
#define EE  262144
#define CC  32
#define HH  64
#define TPB 256
#define WPB 4            // waves per block
#define WIN 256          // edges per wave window
#define ACCR 32          // accumulator rows per wave

typedef _Float16 f16;
typedef _Float16 f16x8 __attribute__((ext_vector_type(8)));
typedef float    f32x4 __attribute__((ext_vector_type(4)));

__device__ __forceinline__ float gelu_tanh(float x){
  float u = 0.7978845608028654f * fmaf(0.044715f * x, x * x, x);
  float e = __expf(2.0f * u);
  float r = __builtin_amdgcn_rcpf(e + 1.0f);
  return x * (1.0f - r);                 // 0.5x(1+tanh u)
}

// ---- pack: f16 copies of W1(+b1, K=8 padded), W2, W3 ----
extern "C" __global__ void magno_pack(const float* __restrict__ W1, const float* __restrict__ b1,
                                      const float* __restrict__ W2, const float* __restrict__ W3,
                                      f16* __restrict__ W1p, f16* __restrict__ W2h, f16* __restrict__ W3h){
  int i = blockIdx.x * blockDim.x + threadIdx.x;
  if (i < HH * HH) W2h[i] = (f16)W2[i];
  if (i < CC * HH) W3h[i] = (f16)W3[i];
  if (i < HH * 8){
    int j = i >> 3, k = i & 7;
    float v = (k < 4) ? W1[j * 4 + k] : (k == 4 ? b1[j] : 0.f);
    W1p[i] = (f16)v;
  }
}

// ---- coef[b,s,m] = softmax_s(scaleMLP(lat_m)) / max(cnt,1) ----
extern "C" __global__ void magno_coef(const float* __restrict__ lat, const int* __restrict__ row_idx,
                                      const float* __restrict__ Ws1, const float* __restrict__ bs1,
                                      const float* __restrict__ Ws2, const float* __restrict__ bs2,
                                      float* __restrict__ coefw){
  int idx = blockIdx.x * blockDim.x + threadIdx.x;
  if (idx >= BB * SS * MM) return;
  int m = idx % MM, s = (idx / MM) % SS, b = idx / (SS * MM);
  const int* rows = row_idx + (size_t)(b * SS + s) * EE;
  int lo = 0, hi = EE;
  while (lo < hi){ int mid = (lo + hi) >> 1; if (rows[mid] < m) lo = mid + 1; else hi = mid; }
  int l0 = lo; hi = EE;
  while (lo < hi){ int mid = (lo + hi) >> 1; if (rows[mid] < m + 1) lo = mid + 1; else hi = mid; }
  float cnt = (float)(lo - l0);
  float la = lat[m * 2 + 0], lb = lat[m * 2 + 1];
  float t[16];
  #pragma unroll
  for (int i = 0; i < 16; i++)
    t[i] = fmaxf(fmaf(la, Ws1[i * 2 + 0], fmaf(lb, Ws1[i * 2 + 1], bs1[i])), 0.f);
  float a0 = bs2[0], a1 = bs2[1], a2 = bs2[2];
  #pragma unroll
  for (int i = 0; i < 16; i++){
    a0 = fmaf(t[i], Ws2[i], a0); a1 = fmaf(t[i], Ws2[16 + i], a1); a2 = fmaf(t[i], Ws2[32 + i], a2);
  }
  float mx = fmaxf(a0, fmaxf(a1, a2));
  float e0 = __expf(a0 - mx), e1 = __expf(a1 - mx), e2 = __expf(a2 - mx);
  float inv = 1.f / (e0 + e1 + e2);
  float sw = (s == 0 ? e0 : (s == 1 ? e1 : e2)) * inv;
  coefw[idx] = sw / fmaxf(cnt, 1.f);
}

extern "C" __global__ void __launch_bounds__(TPB, 2)
magno_main(const float* __restrict__ x_coord,
           const float* __restrict__ pndata,
           const float* __restrict__ lat,
           const int* __restrict__ nbr_idx,
           const int* __restrict__ row_idx,
           const float* __restrict__ W_lift,
           const float* __restrict__ b_lift,
           const float* __restrict__ b2,
           const float* __restrict__ b3,
           const f16* __restrict__ W1p,
           const f16* __restrict__ W2h,
           const f16* __restrict__ W3h,
           const float* __restrict__ coefw,
           float* __restrict__ out)
{
  __shared__ __align__(16) f16   hbuf[WPB][64 * 64];   // t8 -> h1 -> h2 (A-layout, XOR-swizzled)
  __shared__ __align__(16) float einfo[WPB][64 * 4];   // {rowLocal, p0, p1, p2} per edge
  __shared__ float accs[WPB][ACCR * CC];

  const int tid  = threadIdx.x;
  const int wv   = tid >> 6;
  const int lane = tid & 63;
  const int g    = lane >> 4;
  const int n    = lane & 15;

  const int wid = blockIdx.x * WPB + wv;               // 6144 windows total
  const int b   = wid / (SS * (EE / WIN));
  const int rem = wid % (SS * (EE / WIN));
  const int s   = rem / (EE / WIN);
  const int e0  = (rem % (EE / WIN)) * WIN;

  const int* rows = row_idx + (size_t)(b * SS + s) * EE;
  const int* nbrs = nbr_idx + (size_t)(b * SS + s) * EE;
  const int rowbase = rows[e0];

  // ---- resident weight fragments ----
  const f16x8 zf = {0,0,0,0,0,0,0,0};
  const f32x4 z4 = {0.f,0.f,0.f,0.f};
  f16x8 w1f[4], w2f[2][4], w3f[2][2];
  #pragma unroll
  for (int nt = 0; nt < 4; nt++){
    f16x8 v = *(const f16x8*)(W1p + (16 * nt + n) * 8);
    w1f[nt] = (g == 0) ? v : zf;
    #pragma unroll
    for (int kt = 0; kt < 2; kt++)
      w2f[kt][nt] = *(const f16x8*)(W2h + (16 * nt + n) * 64 + 32 * kt + 8 * g);
  }
  #pragma unroll
  for (int nt = 0; nt < 2; nt++)
    #pragma unroll
    for (int kt = 0; kt < 2; kt++)
      w3f[kt][nt] = *(const f16x8*)(W3h + (16 * nt + n) * 64 + 32 * kt + 8 * g);

  float b2v[4];
  #pragma unroll
  for (int nt = 0; nt < 4; nt++) b2v[nt] = b2[16 * nt + n];
  float b3v[2], wl0[2], wl1[2], wl2[2], blv[2];
  #pragma unroll
  for (int nt = 0; nt < 2; nt++){
    int c = 16 * nt + n;
    b3v[nt] = b3[c]; blv[nt] = b_lift[c];
    wl0[nt] = W_lift[c * 3 + 0]; wl1[nt] = W_lift[c * 3 + 1]; wl2[nt] = W_lift[c * 3 + 2];
  }

  // ---- zero the per-wave accumulator ----
  float4* ap = (float4*)accs[wv];
  #pragma unroll
  for (int i = 0; i < 4; i++) ap[i * 64 + lane] = make_float4(0.f, 0.f, 0.f, 0.f);

  f16* hb = hbuf[wv];

  for (int kk = 0; kk < 4; kk++){
    const int f   = e0 + kk * 64 + lane;
    const int row = rows[f];
    const int nbr = nbrs[f];
    const float2 la = *(const float2*)(lat + row * 2);
    const float2 xc = *(const float2*)(x_coord + ((size_t)b * NN + nbr) * 2);
    const float p0 = pndata[((size_t)b * NN + nbr) * 3 + 0];
    const float p1 = pndata[((size_t)b * NN + nbr) * 3 + 1];
    const float p2 = pndata[((size_t)b * NN + nbr) * 3 + 2];
    *(float4*)(einfo[wv] + lane * 4) =
        make_float4(__int_as_float(row - rowbase), p0, p1, p2);

    // stage t-vector (A-layout K=8): row = edge-in-batch = lane
    f16x8 t8 = {(f16)xc.x, (f16)xc.y, (f16)la.x, (f16)la.y, (f16)1.0f, (f16)0.f, (f16)0.f, (f16)0.f};
    *(f16x8*)(hb + lane * 8) = t8;

    f16x8 a1[4];
    #pragma unroll
    for (int mt = 0; mt < 4; mt++){
      f16x8 v = *(const f16x8*)(hb + (16 * mt + n) * 8);
      a1[mt] = (g == 0) ? v : zf;
    }

    // ---- layer 1 (MFMA, K=8 padded) + gelu -> h1 into hbuf ----
    #pragma unroll
    for (int nt = 0; nt < 4; nt++){
      #pragma unroll
      for (int mt = 0; mt < 4; mt++){
        f32x4 d = __builtin_amdgcn_mfma_f32_16x16x32_f16(a1[mt], w1f[nt], z4, 0, 0, 0);
        #pragma unroll
        for (int r = 0; r < 4; r++){
          int edge = 16 * mt + 4 * g + r;
          int j = 16 * nt + n;
          hb[edge * 64 + (j ^ ((edge & 7) << 3))] = (f16)gelu_tanh(d[r]);
        }
      }
    }

    // ---- layer 2: A-frags from LDS, MFMA, gelu -> h2 overwrites hbuf ----
    f16x8 a2[4][2];
    #pragma unroll
    for (int mt = 0; mt < 4; mt++){
      int rw = 16 * mt + n;
      #pragma unroll
      for (int kt = 0; kt < 2; kt++)
        a2[mt][kt] = *(const f16x8*)(hb + rw * 64 + ((32 * kt + 8 * g) ^ ((rw & 7) << 3)));
    }
    #pragma unroll
    for (int nt = 0; nt < 4; nt++){
      #pragma unroll
      for (int mt = 0; mt < 4; mt++){
        f32x4 d = __builtin_amdgcn_mfma_f32_16x16x32_f16(a2[mt][0], w2f[0][nt], z4, 0, 0, 0);
        d = __builtin_amdgcn_mfma_f32_16x16x32_f16(a2[mt][1], w2f[1][nt], d, 0, 0, 0);
        #pragma unroll
        for (int r = 0; r < 4; r++){
          int edge = 16 * mt + 4 * g + r;
          int j = 16 * nt + n;
          hb[edge * 64 + (j ^ ((edge & 7) << 3))] = (f16)gelu_tanh(d[r] + b2v[nt]);
        }
      }
    }

    // ---- layer 3 + epilogue ----
    #pragma unroll
    for (int mt = 0; mt < 4; mt++){
      int rw = 16 * mt + n;
      f16x8 a3k0 = *(const f16x8*)(hb + rw * 64 + ((      8 * g) ^ ((rw & 7) << 3)));
      f16x8 a3k1 = *(const f16x8*)(hb + rw * 64 + ((32 + 8 * g) ^ ((rw & 7) << 3)));
      f32x4 d0 = __builtin_amdgcn_mfma_f32_16x16x32_f16(a3k0, w3f[0][0], z4, 0, 0, 0);
      d0 = __builtin_amdgcn_mfma_f32_16x16x32_f16(a3k1, w3f[1][0], d0, 0, 0, 0);
      f32x4 d1 = __builtin_amdgcn_mfma_f32_16x16x32_f16(a3k0, w3f[0][1], z4, 0, 0, 0);
      d1 = __builtin_amdgcn_mfma_f32_16x16x32_f16(a3k1, w3f[1][1], d1, 0, 0, 0);
      #pragma unroll
      for (int r = 0; r < 4; r++){
        int edge = 16 * mt + 4 * g + r;
        float4 ei = *(const float4*)(einfo[wv] + edge * 4);
        int rl = __float_as_int(ei.x);
        #pragma unroll
        for (int nt = 0; nt < 2; nt++){
          float pv = fmaf(ei.y, wl0[nt], fmaf(ei.z, wl1[nt], fmaf(ei.w, wl2[nt], blv[nt])));
          float dv = (nt == 0) ? d0[r] : d1[r];
          float contrib = (dv + b3v[nt]) * pv;
          if (rl < ACCR){
            unsafeAtomicAdd(&accs[wv][rl * CC + 16 * nt + n], contrib);
          } else {
            float cf = coefw[(size_t)(b * SS + s) * MM + rowbase + rl];
            unsafeAtomicAdd(out + ((size_t)b * MM + rowbase + rl) * CC + 16 * nt + n, contrib * cf);
          }
        }
      }
    }
  }

  // ---- flush wave accumulator (coef-weighted) ----
  const float* cfb = coefw + (size_t)(b * SS + s) * MM + rowbase;
  #pragma unroll
  for (int i = 0; i < 16; i++){
    int idx = i * 64 + lane;
    float v = accs[wv][idx];
    if (v != 0.f){
      int r = idx >> 5, ch = idx & 31;
      unsafeAtomicAdd(out + ((size_t)b * MM + rowbase + r) * CC + ch, v * cfb[r]);
    }
  }
}

extern "C" void kernel_launch(void* const* d_in, const int* in_sizes, int n_in,
                              void* d_out, int out_size, void* d_ws, size_t ws_size,
                              hipStream_t stream)
{
  const float* x_coord = (const float*)d_in[0];
  const float* pndata  = (const float*)d_in[1];
  const float* lat     = (const float*)d_in[2];
  const int*   nbr_idx = (const int*)d_in[3];
  const int*   row_idx = (const int*)d_in[4];
  const float* W_lift  = (const float*)d_in[5];
  const float* b_lift  = (const float*)d_in[6];
  const float* W1      = (const float*)d_in[7];
  const float* b1      = (const float*)d_in[8];
  const float* W2      = (const float*)d_in[9];
  const float* b2      = (const float*)d_in[10];
  const float* W3      = (const float*)d_in[11];
  const float* b3      = (const float*)d_in[12];
  const float* Ws1     = (const float*)d_in[13];
  const float* bs1     = (const float*)d_in[14];
  const float* Ws2     = (const float*)d_in[15];
  const float* bs2     = (const float*)d_in[16];
  float* out = (float*)d_out;

  // ws layout: W2h 8KB | W3h 4KB | W1p 1KB | pad | coef 384KB
  f16*   W2h   = (f16*)d_ws;
  f16*   W3h   = (f16*)((char*)d_ws + 8192);
  f16*   W1p   = (f16*)((char*)d_ws + 12288);
  float* coefw = (float*)((char*)d_ws + 16384);

  hipMemsetAsync(d_out, 0, (size_t)out_size * sizeof(float), stream);
  hipLaunchKernelGGL(magno_pack, dim3(16), dim3(256), 0, stream, W1, b1, W2, W3, W1p, W2h, W3h);
  hipLaunchKernelGGL(magno_coef, dim3((BB * SS * MM + 255) / 256), dim3(256), 0, stream,
                     lat, row_idx, Ws1, bs1, Ws2, bs2, coefw);
  hipLaunchKernelGGL(magno_main, dim3(BB * SS * (EE / WIN) / WPB), dim3(TPB), 0, stream,
                     x_coord, pndata, lat, nbr_idx, row_idx,
                     W_lift, b_lift, b2, b3, W1p, W2h, W3h, coefw, out);
}

// Round 6
// 199.197 us; speedup vs baseline: 3.3202x; 1.7362x over previous
//
#include <hip/hip_runtime.h>
#include <stdint.h>

#define BB  2
#define NN  100000
#define MM  16384
#define SS  3
#define EE  262144
#define CC  32
#define HH  64
#define TPB 256
#define WPB 4            // waves per block
#define WIN 256          // edges per wave window
#define ACCR 28          // accumulator rows per wave

typedef _Float16 f16;
typedef _Float16 f16x8 __attribute__((ext_vector_type(8)));
typedef float    f32x4 __attribute__((ext_vector_type(4)));

// gelu = x * (1 - 1/(1 + 2^(K1*x + K3*x^3)))  (exact tanh-gelu reformulation)
__device__ __forceinline__ float gelu_tanh(float x){
  float u = x * fmaf(0.10294232f, x * x, 2.30218762f);
#if __has_builtin(__builtin_amdgcn_exp2f)
  float e = __builtin_amdgcn_exp2f(u);
#else
  float e = exp2f(u);
#endif
  float r = __builtin_amdgcn_rcpf(e + 1.0f);
  return x - x * r;
}

// ---- pack: f16 W1(+b1, K=8 pad), W2, W3, W_lift(+b_lift, K=8 pad at k=4..7) ----
extern "C" __global__ void magno_pack(const float* __restrict__ W1, const float* __restrict__ b1,
                                      const float* __restrict__ W2, const float* __restrict__ W3,
                                      const float* __restrict__ W_lift, const float* __restrict__ b_lift,
                                      f16* __restrict__ W1p, f16* __restrict__ W2h,
                                      f16* __restrict__ W3h, f16* __restrict__ WLp){
  int i = blockIdx.x * blockDim.x + threadIdx.x;
  if (i < HH * HH) W2h[i] = (f16)W2[i];
  if (i < CC * HH) W3h[i] = (f16)W3[i];
  if (i < HH * 8){
    int j = i >> 3, k = i & 7;
    float v = (k < 4) ? W1[j * 4 + k] : (k == 4 ? b1[j] : 0.f);
    W1p[i] = (f16)v;
  }
  if (i < CC * 8){
    int c = i >> 3, k = i & 7;
    float v = (k == 4) ? b_lift[c] : (k >= 5 ? W_lift[c * 3 + (k - 5)] : 0.f);
    WLp[i] = (f16)v;
  }
}

// ---- coef[b,s,m] = softmax_s(scaleMLP(lat_m)) / max(cnt,1) ----
extern "C" __global__ void magno_coef(const float* __restrict__ lat, const int* __restrict__ row_idx,
                                      const float* __restrict__ Ws1, const float* __restrict__ bs1,
                                      const float* __restrict__ Ws2, const float* __restrict__ bs2,
                                      float* __restrict__ coefw){
  int idx = blockIdx.x * blockDim.x + threadIdx.x;
  if (idx >= BB * SS * MM) return;
  int m = idx % MM, s = (idx / MM) % SS, b = idx / (SS * MM);
  const int* rows = row_idx + (size_t)(b * SS + s) * EE;
  int lo = 0, hi = EE;
  while (lo < hi){ int mid = (lo + hi) >> 1; if (rows[mid] < m) lo = mid + 1; else hi = mid; }
  int l0 = lo; hi = EE;
  while (lo < hi){ int mid = (lo + hi) >> 1; if (rows[mid] < m + 1) lo = mid + 1; else hi = mid; }
  float cnt = (float)(lo - l0);
  float la = lat[m * 2 + 0], lb = lat[m * 2 + 1];
  float t[16];
  #pragma unroll
  for (int i = 0; i < 16; i++)
    t[i] = fmaxf(fmaf(la, Ws1[i * 2 + 0], fmaf(lb, Ws1[i * 2 + 1], bs1[i])), 0.f);
  float a0 = bs2[0], a1 = bs2[1], a2 = bs2[2];
  #pragma unroll
  for (int i = 0; i < 16; i++){
    a0 = fmaf(t[i], Ws2[i], a0); a1 = fmaf(t[i], Ws2[16 + i], a1); a2 = fmaf(t[i], Ws2[32 + i], a2);
  }
  float mx = fmaxf(a0, fmaxf(a1, a2));
  float e0 = __expf(a0 - mx), e1 = __expf(a1 - mx), e2 = __expf(a2 - mx);
  float inv = 1.f / (e0 + e1 + e2);
  float sw = (s == 0 ? e0 : (s == 1 ? e1 : e2)) * inv;
  coefw[idx] = sw / fmaxf(cnt, 1.f);
}

extern "C" __global__ void __launch_bounds__(TPB, 3)
magno_main(const float* __restrict__ x_coord,
           const float* __restrict__ pndata,
           const float* __restrict__ lat,
           const int* __restrict__ nbr_idx,
           const int* __restrict__ row_idx,
           const float* __restrict__ b2,
           const float* __restrict__ b3,
           const f16* __restrict__ W1p,
           const f16* __restrict__ W2h,
           const f16* __restrict__ W3h,
           const f16* __restrict__ WLp,
           const float* __restrict__ coefw,
           float* __restrict__ out)
{
  __shared__ __align__(16) f16   hbuf[WPB][64 * 64];   // h1 -> h2 (A-layout, XOR-swizzled)  32KB
  __shared__ __align__(16) f16   tst [WPB][64 * 8];    // staged t-vectors                    4KB
  __shared__ ushort rloc[WPB][2][64];                  // local row per edge (double-buf)     1KB
  __shared__ float  accs[WPB][ACCR * CC];              // per-wave row accumulators        14.3KB

  const int tid  = threadIdx.x;
  const int wv   = tid >> 6;
  const int lane = tid & 63;
  const int g    = lane >> 4;
  const int n    = lane & 15;

  const int wid = blockIdx.x * WPB + wv;
  const int b   = wid / (SS * (EE / WIN));
  const int rem = wid % (SS * (EE / WIN));
  const int s   = rem / (EE / WIN);
  const int e0  = (rem % (EE / WIN)) * WIN;

  const int* rows = row_idx + (size_t)(b * SS + s) * EE;
  const int* nbrs = nbr_idx + (size_t)(b * SS + s) * EE;
  const int rowbase = rows[e0];
  const size_t cofs    = (size_t)(b * SS + s) * MM + rowbase;
  const size_t outbase = ((size_t)b * MM + rowbase) * CC;

  const f16x8 zf = {0,0,0,0,0,0,0,0};
  const f32x4 z4 = {0.f,0.f,0.f,0.f};

  // ---- resident weight fragments ----
  f16x8 w1f[4], w2f[2][4], w3f[2][2], wlf[2];
  #pragma unroll
  for (int nt = 0; nt < 4; nt++){
    f16x8 v = *(const f16x8*)(W1p + (16 * nt + n) * 8);
    w1f[nt] = (g == 0) ? v : zf;
    #pragma unroll
    for (int kt = 0; kt < 2; kt++)
      w2f[kt][nt] = *(const f16x8*)(W2h + (16 * nt + n) * 64 + 32 * kt + 8 * g);
  }
  #pragma unroll
  for (int nt = 0; nt < 2; nt++){
    #pragma unroll
    for (int kt = 0; kt < 2; kt++)
      w3f[kt][nt] = *(const f16x8*)(W3h + (16 * nt + n) * 64 + 32 * kt + 8 * g);
    f16x8 v = *(const f16x8*)(WLp + (16 * nt + n) * 8);
    wlf[nt] = (g == 0) ? v : zf;
  }
  float b2v[4];
  #pragma unroll
  for (int nt = 0; nt < 4; nt++) b2v[nt] = b2[16 * nt + n];
  float b3v[2];
  #pragma unroll
  for (int nt = 0; nt < 2; nt++) b3v[nt] = b3[16 * nt + n];

  // ---- zero per-wave accumulator ----
  #pragma unroll
  for (int i = 0; i < ACCR * CC / 64; i++) accs[wv][i * 64 + lane] = 0.f;

  f16* hb = hbuf[wv];
  f16* ts = tst[wv];

  // ---- prologue: stage edge batch 0 ----
  {
    int f0 = e0 + lane;
    int row = rows[f0], nbr = nbrs[f0];
    float2 la = *(const float2*)(lat + row * 2);
    float2 xc = *(const float2*)(x_coord + ((size_t)b * NN + nbr) * 2);
    const float* pp = pndata + ((size_t)b * NN + nbr) * 3;
    float p0 = pp[0], p1 = pp[1], p2 = pp[2];
    f16x8 t8 = {(f16)xc.x, (f16)xc.y, (f16)la.x, (f16)la.y, (f16)1.0f, (f16)p0, (f16)p1, (f16)p2};
    *(f16x8*)(ts + lane * 8) = t8;
    rloc[wv][0][lane] = (ushort)(row - rowbase);
  }

  for (int kk = 0; kk < 4; kk++){
    const int cur = kk & 1;

    // ---- prefetch next batch's gathers (hide under L1 compute) ----
    int row2 = 0, nbr2 = 0; float2 la2 = {0.f,0.f}, xc2 = {0.f,0.f};
    float q0 = 0.f, q1 = 0.f, q2 = 0.f;
    if (kk < 3){
      int f2 = e0 + (kk + 1) * 64 + lane;
      row2 = rows[f2]; nbr2 = nbrs[f2];
      la2 = *(const float2*)(lat + row2 * 2);
      xc2 = *(const float2*)(x_coord + ((size_t)b * NN + nbr2) * 2);
      const float* pp = pndata + ((size_t)b * NN + nbr2) * 3;
      q0 = pp[0]; q1 = pp[1]; q2 = pp[2];
    }

    // ---- a1 frags (kept live for pv-MFMA in epilogue) ----
    f16x8 a1[4];
    #pragma unroll
    for (int mt = 0; mt < 4; mt++){
      f16x8 v = *(const f16x8*)(ts + (16 * mt + n) * 8);
      a1[mt] = (g == 0) ? v : zf;
    }

    // ---- layer 1 ----
    #pragma unroll
    for (int mt = 0; mt < 4; mt++){
      #pragma unroll
      for (int nt = 0; nt < 4; nt++){
        f32x4 d = __builtin_amdgcn_mfma_f32_16x16x32_f16(a1[mt], w1f[nt], z4, 0, 0, 0);
        #pragma unroll
        for (int r = 0; r < 4; r++){
          int edge = 16 * mt + 4 * g + r;
          int j = 16 * nt + n;
          hb[edge * 64 + (j ^ ((edge & 7) << 3))] = (f16)gelu_tanh(d[r]);
        }
      }
    }

    // ---- stage next batch (prefetched data has landed under L1) ----
    if (kk < 3){
      f16x8 t8 = {(f16)xc2.x, (f16)xc2.y, (f16)la2.x, (f16)la2.y, (f16)1.0f, (f16)q0, (f16)q1, (f16)q2};
      *(f16x8*)(ts + lane * 8) = t8;
      rloc[wv][cur ^ 1][lane] = (ushort)(row2 - rowbase);
    }

    // ---- layer 2 (mt-outer: only 2 A-frags live) ----
    #pragma unroll
    for (int mt = 0; mt < 4; mt++){
      int rw = 16 * mt + n;
      f16x8 a2k0 = *(const f16x8*)(hb + rw * 64 + ((     8 * g) ^ ((rw & 7) << 3)));
      f16x8 a2k1 = *(const f16x8*)(hb + rw * 64 + ((32 + 8 * g) ^ ((rw & 7) << 3)));
      #pragma unroll
      for (int nt = 0; nt < 4; nt++){
        f32x4 d = __builtin_amdgcn_mfma_f32_16x16x32_f16(a2k0, w2f[0][nt], z4, 0, 0, 0);
        d = __builtin_amdgcn_mfma_f32_16x16x32_f16(a2k1, w2f[1][nt], d, 0, 0, 0);
        #pragma unroll
        for (int r = 0; r < 4; r++){
          int edge = 16 * mt + 4 * g + r;
          int j = 16 * nt + n;
          hb[edge * 64 + (j ^ ((edge & 7) << 3))] = (f16)gelu_tanh(d[r] + b2v[nt]);
        }
      }
    }

    // ---- layer 3 + pv-MFMA + run-merged atomic epilogue ----
    #pragma unroll
    for (int mt = 0; mt < 4; mt++){
      int rw = 16 * mt + n;
      f16x8 a3k0 = *(const f16x8*)(hb + rw * 64 + ((     8 * g) ^ ((rw & 7) << 3)));
      f16x8 a3k1 = *(const f16x8*)(hb + rw * 64 + ((32 + 8 * g) ^ ((rw & 7) << 3)));
      f32x4 d0 = __builtin_amdgcn_mfma_f32_16x16x32_f16(a3k0, w3f[0][0], z4, 0, 0, 0);
      d0 = __builtin_amdgcn_mfma_f32_16x16x32_f16(a3k1, w3f[1][0], d0, 0, 0, 0);
      f32x4 d1 = __builtin_amdgcn_mfma_f32_16x16x32_f16(a3k0, w3f[0][1], z4, 0, 0, 0);
      d1 = __builtin_amdgcn_mfma_f32_16x16x32_f16(a3k1, w3f[1][1], d1, 0, 0, 0);
      f32x4 pv0 = __builtin_amdgcn_mfma_f32_16x16x32_f16(a1[mt], wlf[0], z4, 0, 0, 0);
      f32x4 pv1 = __builtin_amdgcn_mfma_f32_16x16x32_f16(a1[mt], wlf[1], z4, 0, 0, 0);

      uint2 rr = *(const uint2*)&rloc[wv][cur][16 * mt + 4 * g];
      int rl[4] = { (int)(rr.x & 0xffff), (int)(rr.x >> 16),
                    (int)(rr.y & 0xffff), (int)(rr.y >> 16) };
      float c0[4], c1[4];
      #pragma unroll
      for (int r = 0; r < 4; r++){
        c0[r] = (d0[r] + b3v[0]) * pv0[r];
        c1[r] = (d1[r] + b3v[1]) * pv1[r];
      }

      auto emitf = [&](int rl_, float s0_, float s1_){
        if (rl_ < ACCR){
          unsafeAtomicAdd(&accs[wv][rl_ * CC + n], s0_);
          unsafeAtomicAdd(&accs[wv][rl_ * CC + 16 + n], s1_);
        } else {
          float cf = coefw[cofs + rl_];
          unsafeAtomicAdd(out + outbase + (size_t)rl_ * CC + n, s0_ * cf);
          unsafeAtomicAdd(out + outbase + (size_t)rl_ * CC + 16 + n, s1_ * cf);
        }
      };

      int crl = rl[0]; float s0 = c0[0], s1 = c1[0];
      #pragma unroll
      for (int r = 1; r < 4; r++){
        if (rl[r] == crl){ s0 += c0[r]; s1 += c1[r]; }
        else { emitf(crl, s0, s1); crl = rl[r]; s0 = c0[r]; s1 = c1[r]; }
      }
      emitf(crl, s0, s1);
    }
  }

  // ---- flush wave accumulator (coef-weighted) ----
  const float* cfb = coefw + cofs;
  #pragma unroll
  for (int i = 0; i < ACCR * CC / 64; i++){
    int idx = i * 64 + lane;
    float v = accs[wv][idx];
    if (v != 0.f){
      int r = idx >> 5, ch = idx & 31;
      unsafeAtomicAdd(out + outbase + r * CC + ch, v * cfb[r]);
    }
  }
}

extern "C" void kernel_launch(void* const* d_in, const int* in_sizes, int n_in,
                              void* d_out, int out_size, void* d_ws, size_t ws_size,
                              hipStream_t stream)
{
  const float* x_coord = (const float*)d_in[0];
  const float* pndata  = (const float*)d_in[1];
  const float* lat     = (const float*)d_in[2];
  const int*   nbr_idx = (const int*)d_in[3];
  const int*   row_idx = (const int*)d_in[4];
  const float* W_lift  = (const float*)d_in[5];
  const float* b_lift  = (const float*)d_in[6];
  const float* W1      = (const float*)d_in[7];
  const float* b1      = (const float*)d_in[8];
  const float* W2      = (const float*)d_in[9];
  const float* b2      = (const float*)d_in[10];
  const float* W3      = (const float*)d_in[11];
  const float* b3      = (const float*)d_in[12];
  const float* Ws1     = (const float*)d_in[13];
  const float* bs1     = (const float*)d_in[14];
  const float* Ws2     = (const float*)d_in[15];
  const float* bs2     = (const float*)d_in[16];
  float* out = (float*)d_out;

  // ws layout: W2h 8KB | W3h 4KB | W1p 1KB | WLp 0.5KB | pad | coef 384KB
  f16*   W2h   = (f16*)d_ws;
  f16*   W3h   = (f16*)((char*)d_ws + 8192);
  f16*   W1p   = (f16*)((char*)d_ws + 12288);
  f16*   WLp   = (f16*)((char*)d_ws + 13312);
  float* coefw = (float*)((char*)d_ws + 16384);

  hipMemsetAsync(d_out, 0, (size_t)out_size * sizeof(float), stream);
  hipLaunchKernelGGL(magno_pack, dim3(16), dim3(256), 0, stream,
                     W1, b1, W2, W3, W_lift, b_lift, W1p, W2h, W3h, WLp);
  hipLaunchKernelGGL(magno_coef, dim3((BB * SS * MM + 255) / 256), dim3(256), 0, stream,
                     lat, row_idx, Ws1, bs1, Ws2, bs2, coefw);
  hipLaunchKernelGGL(magno_main, dim3(BB * SS * (EE / WIN) / WPB), dim3(TPB), 0, stream,
                     x_coord, pndata, lat, nbr_idx, row_idx,
                     b2, b3, W1p, W2h, W3h, WLp, coefw, out);
}